// Round 1
// baseline (529.118 us; speedup 1.0000x reference)
//
#include <hip/hip_runtime.h>

// OTPE single timestep on MI355X.
// Inputs: x[8192], W[8192,4096], u[4096], E[8192,4096], R_hat[8192,4096],
//         g_bar[4096], ratio[1]  (all f32)
// Outputs (concat): s[4096], u_new[4096], E_new[8192,4096], R_new[8192,4096],
//                   g_bar_new[4096], ratio_new[1]
//
// Memory-bound: ~671 MB of HBM traffic -> ~107 us roofline at 6.3 TB/s.

#define SIG_TAU 0.8807970779778823f  // sigmoid(2.0) in f32

constexpr int N_IN  = 8192;
constexpr int N_OUT = 4096;
constexpr int NCG   = N_OUT / 4;       // 1024 float4 column-groups
constexpr int ROWS_PER_CHUNK = 64;

// Output offsets (floats)
constexpr size_t OFF_S     = 0;
constexpr size_t OFF_U     = (size_t)N_OUT;                       // 4096
constexpr size_t OFF_E     = (size_t)2 * N_OUT;                   // 8192
constexpr size_t OFF_R     = OFF_E + (size_t)N_IN * N_OUT;        // 33562624
constexpr size_t OFF_G     = OFF_R + (size_t)N_IN * N_OUT;        // 67117056
constexpr size_t OFF_RATIO = OFF_G + (size_t)N_OUT;               // 67121152

// Split-K matvec: out[j] = sum_i x[i]*W[i,j]. Coalesced float4 column reads;
// per-row x[i] is block-uniform (scalar load path). Partials via atomicAdd.
__global__ __launch_bounds__(256) void matvec_partial(
    const float* __restrict__ x, const float4* __restrict__ W4,
    float* __restrict__ acc) {
    const int cg   = blockIdx.x * 256 + threadIdx.x;   // 0..1023
    const int row0 = blockIdx.y * ROWS_PER_CHUNK;
    float4 a = make_float4(0.f, 0.f, 0.f, 0.f);
#pragma unroll 8
    for (int r = 0; r < ROWS_PER_CHUNK; ++r) {
        const float  xv = x[row0 + r];
        const float4 w  = W4[(size_t)(row0 + r) * NCG + cg];
        a.x = fmaf(xv, w.x, a.x);
        a.y = fmaf(xv, w.y, a.y);
        a.z = fmaf(xv, w.z, a.z);
        a.w = fmaf(xv, w.w, a.w);
    }
    float* dst = acc + (size_t)cg * 4;
    atomicAdd(dst + 0, a.x);
    atomicAdd(dst + 1, a.y);
    atomicAdd(dst + 2, a.z);
    atomicAdd(dst + 3, a.w);
}

// Per-column finalize: spike, surrogate grad, soft reset, g_bar/ratio update.
__global__ __launch_bounds__(256) void finalize(
    const float* __restrict__ acc, const float* __restrict__ u,
    const float* __restrict__ g_bar, const float* __restrict__ ratio,
    float* __restrict__ out, float* __restrict__ sg_ws) {
    const int j = blockIdx.x * 256 + threadIdx.x;
    if (j >= N_OUT) return;
    const float u_pre = fmaf(SIG_TAU, u[j], acc[j]);
    const float s     = (u_pre >= 1.0f) ? 1.0f : 0.0f;
    const float t     = 1.0f / fmaf(10.0f, fabsf(u_pre - 1.0f), 1.0f);
    const float sg    = t * t;                 // surrogate ds/du_pre
    const float u_new = u_pre - s;             // soft reset, V_TH=1

    const float r0        = SIG_TAU * ratio[0];
    const float ratio_new = r0 + 1.0f;
    const float r         = r0 / ratio_new;
    // ds_du_prev / sig_tau == sg
    const float g_new = fmaf(r, g_bar[j], (1.0f - r) * sg);

    out[OFF_S + j] = s;
    out[OFF_U + j] = u_new;
    out[OFF_G + j] = g_new;
    sg_ws[j] = sg;
    if (j == 0) out[OFF_RATIO] = ratio_new;
}

// Big elementwise pass: E_new = sig_tau*E + x[i];
// R_new = sig_tau*R_hat + sg[j]*E_new  (== sig_tau*R_hat + ds_du_prev*E + x*sg)
__global__ __launch_bounds__(256) void elemwise(
    const float* __restrict__ x, const float4* __restrict__ E4,
    const float4* __restrict__ R4, const float4* __restrict__ sg4,
    float4* __restrict__ Enew4, float4* __restrict__ Rnew4) {
    const size_t total  = (size_t)N_IN * NCG;  // 8,388,608 float4 groups
    const size_t stride = (size_t)gridDim.x * blockDim.x;
    for (size_t idx = (size_t)blockIdx.x * blockDim.x + threadIdx.x;
         idx < total; idx += stride) {
        const int i  = (int)(idx >> 10);        // row (x index), NCG=1024
        const int cg = (int)(idx & (NCG - 1));  // column group
        const float  xv = x[i];                 // broadcast within wave
        const float4 s4 = sg4[cg];              // 16 KB table, cache-resident
        const float4 e  = E4[idx];
        const float4 rr = R4[idx];
        float4 en, rn;
        en.x = fmaf(SIG_TAU, e.x, xv);
        en.y = fmaf(SIG_TAU, e.y, xv);
        en.z = fmaf(SIG_TAU, e.z, xv);
        en.w = fmaf(SIG_TAU, e.w, xv);
        rn.x = fmaf(s4.x, en.x, SIG_TAU * rr.x);
        rn.y = fmaf(s4.y, en.y, SIG_TAU * rr.y);
        rn.z = fmaf(s4.z, en.z, SIG_TAU * rr.z);
        rn.w = fmaf(s4.w, en.w, SIG_TAU * rr.w);
        Enew4[idx] = en;
        Rnew4[idx] = rn;
    }
}

extern "C" void kernel_launch(void* const* d_in, const int* in_sizes, int n_in,
                              void* d_out, int out_size, void* d_ws, size_t ws_size,
                              hipStream_t stream) {
    const float* x     = (const float*)d_in[0];
    const float* W     = (const float*)d_in[1];
    const float* u     = (const float*)d_in[2];
    const float* E     = (const float*)d_in[3];
    const float* R_hat = (const float*)d_in[4];
    const float* g_bar = (const float*)d_in[5];
    const float* ratio = (const float*)d_in[6];
    float* out = (float*)d_out;

    float* acc = (float*)d_ws;        // [4096] matvec accumulator
    float* sg  = acc + N_OUT;         // [4096] surrogate grad

    // ws is poisoned 0xAA before every timed call -> zero the accumulator.
    hipMemsetAsync(acc, 0, N_OUT * sizeof(float), stream);

    dim3 g1(NCG / 256, N_IN / ROWS_PER_CHUNK);  // (4, 128) = 512 blocks
    matvec_partial<<<g1, 256, 0, stream>>>(x, (const float4*)W, acc);

    finalize<<<N_OUT / 256, 256, 0, stream>>>(acc, u, g_bar, ratio, out, sg);

    elemwise<<<4096, 256, 0, stream>>>(
        x, (const float4*)E, (const float4*)R_hat, (const float4*)sg,
        (float4*)(out + OFF_E), (float4*)(out + OFF_R));
}